// Round 1
// 6857.622 us; speedup vs baseline: 1.0753x; 1.0753x over previous
//
#include <hip/hip_runtime.h>
#include <hip/hip_cooperative_groups.h>
#include <stdint.h>

namespace cg = cooperative_groups;

// Problem constants
#define BB   64
#define TTT  250
#define INN  1024
#define HIDD 2048
#define OUTT 256

#define DECAYF 0.951229424500714f   // exp(-1/20)
#define ALPHAF 0.951229424500714f
#define LRF    1e-4f
#define WDF    0.01f
#define SCLF   0.2f

// d_out offsets (float elements)
#define O_L1SEQ 0
#define O_L2SEQ 32768000
#define O_V1    36864000
#define O_V2    36995072
#define O_L1TR  37011456
#define O_L2TR  37142528

// ws layout (byte offsets), parity-double-buffered cross-block staging (~1.5 MB)
#define WS_INTRT 0          // bf16 [2][1024][64]  in_tr transposed (B-op for w_in update)
#define WS_XB    262144     // bf16 [2][64][1024]  x_t as bf16 (A-op for gemm1)
#define WS_L1B   524288     // bf16 [2][64][2048]  l1 spikes (A-op for gemm2)
#define WS_L1TT  1048576    // bf16 [2][2048][64]  l1_tr transposed (B-op for w_hid update)

#define NB1 64     // layer-1 blocks: 32 h each, w_in slice resident
#define NB2 16     // layer-2 blocks: 16 o each, w_hid slice resident
#define NBLK 80
#define NTHR 512   // 8 waves

typedef __attribute__((ext_vector_type(8))) short short8v;
typedef __attribute__((ext_vector_type(4))) float float4v;

__device__ inline short f2bf(float f) {
  union { float f; uint32_t u; } c; c.f = f;
  uint32_t u = c.u + 0x7fffu + ((c.u >> 16) & 1u);  // RNE
  return (short)(u >> 16);
}

// XOR swizzles: 8-element (16 B) chunks XOR'd with (row&7) -> bank-conflict-free
// MFMA fragment reads (lanes 0-15 read 16 different rows at the same k-chunk).
__device__ inline int swz1024(int row, int k) {
  return row * 1024 + ((((k) >> 3) ^ (row & 7)) << 3) + ((k) & 7);
}
__device__ inline int swz2048(int row, int k) {
  return row * 2048 + ((((k) >> 3) ^ (row & 7)) << 3) + ((k) & 7);
}
__device__ inline int swz64(int row, int k) {
  return row * 64 + ((((k) >> 3) ^ (row & 7)) << 3) + ((k) & 7);
}

struct SG1 {                 // layer-1 block LDS (86528 B)
  short winb[32 * 1024];     // bf16 shadow of w_in slice, swizzled
  float v1s[64 * 33];        // v1 state, padded
  float l1trs[64 * 33];      // l1_tr f32 state, padded
  short l1trT[32 * 64];      // l1_tr^T bf16 (A-op for w_in update), swizzled
};
struct SG2 {                 // layer-2 block LDS (80384 B)
  short whb[16 * 2048];      // bf16 shadow of w_hid slice, swizzled
  float v2s[64 * 17];
  float l2trs[64 * 17];
  short l2trT[16 * 64];      // swizzled
  float red[4 * 256];        // K-split reduce scratch
};

// Persistent kernel. Phase t: layer-1 blocks do step t (gemm1->LIF1->w_in update
// -> prep x/in_tr for t+1); layer-2 blocks do step t-1 (gemm2->LIF2->w_hid update).
// One grid.sync per phase; 251 phases + prologue.
__global__ __launch_bounds__(NTHR, 2) void kmain(const float* __restrict__ x,
                                                 const float* __restrict__ w_in,
                                                 const float* __restrict__ w_hid,
                                                 float* __restrict__ out,
                                                 char* __restrict__ ws) {
  __shared__ __align__(16) char smem[86528];
  cg::grid_group grid = cg::this_grid();
  const int bid = blockIdx.x, tid = threadIdx.x;
  const int lane = tid & 63, wv = tid >> 6;
  const int mr = lane & 15, q = lane >> 4;

  if (bid < NB1) {
    // ---------------- layer-1 block: owns w_in rows [h0, h0+32) ----------------
    SG1& S = *(SG1*)smem;
    const int h0 = bid * 32;
    const int bt = wv & 3, ht = wv >> 2;   // wave tile: b-tile, h-tile
    float wreg[64];                        // f32 w_in master: [j=0..15 i-tiles][r=0..3 h-rows]
    float itr0, itr1;                      // thread-private in_tr state (2 elements)

    // prologue: load w_in slice -> regs + bf16 LDS shadow
#pragma unroll
    for (int j = 0; j < 16; j++) {
      const int it = (wv & 3) * 16 + j;
      const int i = it * 16 + mr;
#pragma unroll
      for (int r = 0; r < 4; r++) {
        const int hl = ht * 16 + q * 4 + r;
        float w = w_in[(h0 + hl) * INN + i];
        wreg[j * 4 + r] = w;
        S.winb[swz1024(hl, i)] = f2bf(w);
      }
    }
    for (int c = tid; c < 64 * 33; c += NTHR) { S.v1s[c] = 0.f; S.l1trs[c] = 0.f; }
    // prep t=0: in_tr(0) = (1-d)*x0; write in_trT[par 0], xb[par 0]
    {
      const int gtid = bid * NTHR + tid;
      const int e2 = gtid * 2, b = e2 >> 10, i = e2 & 1023;
      float2 xv = *(const float2*)(x + (b * TTT + 0) * INN + i);
      itr0 = (1.f - DECAYF) * xv.x;
      itr1 = (1.f - DECAYF) * xv.y;
      short* intT = (short*)(ws + WS_INTRT);
      short* xbp = (short*)(ws + WS_XB);
      short2 xb2; xb2.x = f2bf(xv.x); xb2.y = f2bf(xv.y);
      *(short2*)(xbp + e2) = xb2;
      intT[i * 64 + b] = f2bf(itr0);
      intT[(i + 1) * 64 + b] = f2bf(itr1);
    }
    grid.sync();

    for (int t = 0; t <= TTT; t++) {
      if (t < TTT) {
        const int p = t & 1;
        const short* xb = (const short*)(ws + WS_XB) + p * (BB * INN);
        // gemm1: cur1[64b x 32h] = x_t @ w_in^T, full K=1024, one 16x16 tile/wave
        float4v acc = {0.f, 0.f, 0.f, 0.f};
        {
          const short* xrow = xb + (bt * 16 + mr) * INN;
          const int brow = ht * 16 + mr;
#pragma unroll 8
          for (int ks = 0; ks < 32; ks++) {
            const int koff = ks * 32 + q * 8;
            short8v af = *(const short8v*)(xrow + koff);
            short8v bf = *(const short8v*)&S.winb[swz1024(brow, koff)];
            acc = __builtin_amdgcn_mfma_f32_16x16x32_bf16(af, bf, acc, 0, 0, 0);
          }
        }
        // LIF1 + trace + publish l1 / l1_tr^T (parity p)
        short* l1bg = (short*)(ws + WS_L1B) + p * (BB * HIDD);
        short* l1ttg = (short*)(ws + WS_L1TT) + p * (HIDD * BB);
        {
          const int hl = ht * 16 + mr, h = h0 + hl;
#pragma unroll
          for (int r = 0; r < 4; r++) {
            const int b = bt * 16 + q * 4 + r;
            float v = ALPHAF * S.v1s[b * 33 + hl] + SCLF * acc[r];
            float z = v > 1.0f ? 1.0f : 0.0f;
            v -= z;
            S.v1s[b * 33 + hl] = v;
            out[O_L1SEQ + (b * TTT + t) * HIDD + h] = z;
            l1bg[b * HIDD + h] = f2bf(z);
            float tr = DECAYF * S.l1trs[b * 33 + hl] + (1.f - DECAYF) * z;
            S.l1trs[b * 33 + hl] = tr;
            short tb = f2bf(tr);
            S.l1trT[swz64(hl, b)] = tb;
            l1ttg[h * 64 + b] = tb;
          }
        }
        __syncthreads();   // l1trT complete; all winb reads done before update writes
        // w_in STDP update: D[32h x 1024i] = l1_tr^T @ in_tr, K=64 (block-local!)
        {
          const short* intT = (const short*)(ws + WS_INTRT) + p * (INN * BB);
          const int arow = ht * 16 + mr;
#pragma unroll
          for (int j = 0; j < 16; j++) {
            const int it = (wv & 3) * 16 + j;
            float4v a2 = {0.f, 0.f, 0.f, 0.f};
#pragma unroll
            for (int ks = 0; ks < 2; ks++) {
              const int koff = ks * 32 + q * 8;
              short8v af = *(const short8v*)&S.l1trT[swz64(arow, koff)];
              short8v bf = *(const short8v*)(intT + (it * 16 + mr) * 64 + koff);
              a2 = __builtin_amdgcn_mfma_f32_16x16x32_bf16(af, bf, a2, 0, 0, 0);
            }
            const int i = it * 16 + mr;
#pragma unroll
            for (int r = 0; r < 4; r++) {
              const int hl = ht * 16 + q * 4 + r;
              float w = wreg[j * 4 + r] * (1.f - LRF * WDF) + (LRF / 64.f) * a2[r];
              wreg[j * 4 + r] = w;
              S.winb[swz1024(hl, i)] = f2bf(w);
            }
          }
        }
        // prep t+1: in_tr update (reg-resident) + x bf16, into parity (t+1)&1
        if (t + 1 < TTT) {
          const int pn = (t + 1) & 1;
          const int gtid = bid * NTHR + tid;
          const int e2 = gtid * 2, b = e2 >> 10, i = e2 & 1023;
          float2 xv = *(const float2*)(x + (b * TTT + (t + 1)) * INN + i);
          itr0 = DECAYF * itr0 + (1.f - DECAYF) * xv.x;
          itr1 = DECAYF * itr1 + (1.f - DECAYF) * xv.y;
          short* intT = (short*)(ws + WS_INTRT) + pn * (INN * BB);
          short* xbp = (short*)(ws + WS_XB) + pn * (BB * INN);
          short2 xb2; xb2.x = f2bf(xv.x); xb2.y = f2bf(xv.y);
          *(short2*)(xbp + e2) = xb2;
          intT[i * 64 + b] = f2bf(itr0);
          intT[(i + 1) * 64 + b] = f2bf(itr1);
        }
      }
      grid.sync();
    }
    // epilogue: flush v1 / l1_tr
    for (int c = tid; c < 64 * 32; c += NTHR) {
      const int b = c >> 5, hl = c & 31;
      out[O_V1 + b * HIDD + h0 + hl] = S.v1s[b * 33 + hl];
      out[O_L1TR + b * HIDD + h0 + hl] = S.l1trs[b * 33 + hl];
    }
  } else {
    // ---------------- layer-2 block: owns w_hid rows [o0, o0+16) ----------------
    SG2& S = *(SG2*)smem;
    const int o0 = (bid - NB1) * 16;
    const int bt = wv & 3, kh = wv >> 2;   // b-tile, K-half
    float wreg[64];                        // f32 w_hid master: [j=0..15 h-tiles][r=0..3 o-rows]

#pragma unroll
    for (int j = 0; j < 16; j++) {
      const int hcol = (wv * 16 + j) * 16 + mr;
#pragma unroll
      for (int r = 0; r < 4; r++) {
        const int ol = q * 4 + r;
        float w = w_hid[(o0 + ol) * HIDD + hcol];
        wreg[j * 4 + r] = w;
        S.whb[swz2048(ol, hcol)] = f2bf(w);
      }
    }
    for (int c = tid; c < 64 * 17; c += NTHR) { S.v2s[c] = 0.f; S.l2trs[c] = 0.f; }
    grid.sync();

    for (int t = 0; t <= TTT; t++) {
      if (t >= 1) {
        const int u = t - 1, p = u & 1;
        const short* l1bg = (const short*)(ws + WS_L1B) + p * (BB * HIDD);
        // gemm2: cur2[64b x 16o] = l1 @ w_hid^T, K=2048 split 2 ways across waves
        float4v acc = {0.f, 0.f, 0.f, 0.f};
        {
          const short* arow = l1bg + (bt * 16 + mr) * HIDD + kh * 1024;
#pragma unroll 8
          for (int ks = 0; ks < 32; ks++) {
            const int kk = kh * 1024 + ks * 32 + q * 8;
            short8v af = *(const short8v*)(arow + ks * 32 + q * 8);
            short8v bf = *(const short8v*)&S.whb[swz2048(mr, kk)];
            acc = __builtin_amdgcn_mfma_f32_16x16x32_bf16(af, bf, acc, 0, 0, 0);
          }
        }
        if (kh == 1) { *(float4v*)&S.red[bt * 256 + lane * 4] = acc; }
        __syncthreads();
        if (kh == 0) {
          float4v o4 = *(const float4v*)&S.red[bt * 256 + lane * 4];
#pragma unroll
          for (int r = 0; r < 4; r++) {
            const int b = bt * 16 + q * 4 + r;
            float v = ALPHAF * S.v2s[b * 17 + mr] + SCLF * (acc[r] + o4[r]);
            float z = v > 1.0f ? 1.0f : 0.0f;
            v -= z;
            S.v2s[b * 17 + mr] = v;
            out[O_L2SEQ + (b * TTT + u) * OUTT + o0 + mr] = z;
            float tr = DECAYF * S.l2trs[b * 17 + mr] + (1.f - DECAYF) * z;
            S.l2trs[b * 17 + mr] = tr;
            S.l2trT[swz64(mr, b)] = f2bf(tr);
          }
        }
        __syncthreads();   // l2trT ready; whb reads done before update writes
        // w_hid STDP update: D[16o x 2048h] = l2_tr^T @ l1_tr, K=64 (block-local)
        {
          const short* l1ttg = (const short*)(ws + WS_L1TT) + p * (HIDD * BB);
#pragma unroll
          for (int j = 0; j < 16; j++) {
            const int htile = wv * 16 + j;
            float4v a2 = {0.f, 0.f, 0.f, 0.f};
#pragma unroll
            for (int ks = 0; ks < 2; ks++) {
              const int koff = ks * 32 + q * 8;
              short8v af = *(const short8v*)&S.l2trT[swz64(mr, koff)];
              short8v bf = *(const short8v*)(l1ttg + (htile * 16 + mr) * 64 + koff);
              a2 = __builtin_amdgcn_mfma_f32_16x16x32_bf16(af, bf, a2, 0, 0, 0);
            }
            const int hcol = htile * 16 + mr;
#pragma unroll
            for (int r = 0; r < 4; r++) {
              const int ol = q * 4 + r;
              float w = wreg[j * 4 + r] * (1.f - LRF * WDF) + (LRF / 64.f) * a2[r];
              wreg[j * 4 + r] = w;
              S.whb[swz2048(ol, hcol)] = f2bf(w);
            }
          }
        }
      }
      grid.sync();
    }
    for (int c = tid; c < 64 * 16; c += NTHR) {
      const int b = c >> 4, ol = c & 15;
      out[O_V2 + b * OUTT + o0 + ol] = S.v2s[b * 17 + ol];
      out[O_L2TR + b * OUTT + o0 + ol] = S.l2trs[b * 17 + ol];
    }
  }
}

extern "C" void kernel_launch(void* const* d_in, const int* in_sizes, int n_in,
                              void* d_out, int out_size, void* d_ws, size_t ws_size,
                              hipStream_t stream) {
  const float* x = (const float*)d_in[0];
  const float* w_in = (const float*)d_in[1];    // read-only now (never mutated)
  const float* w_hid = (const float*)d_in[2];
  float* out = (float*)d_out;
  char* ws = (char*)d_ws;

  void* args[] = {(void*)&x, (void*)&w_in, (void*)&w_hid, (void*)&out, (void*)&ws};
  hipLaunchCooperativeKernel(reinterpret_cast<void*>(kmain), dim3(NBLK), dim3(NTHR),
                             args, 0, stream);
}

// Round 2
// 5504.069 us; speedup vs baseline: 1.3397x; 1.2459x over previous
//
#include <hip/hip_runtime.h>
#include <hip/hip_cooperative_groups.h>
#include <stdint.h>

namespace cg = cooperative_groups;

// Problem constants
#define BB   64
#define TTT  250
#define INN  1024
#define HIDD 2048
#define OUTT 256

#define DECAYF 0.951229424500714f   // exp(-1/20)
#define ALPHAF 0.951229424500714f
#define LRF    1e-4f
#define WDF    0.01f
#define SCLF   0.2f

// d_out offsets (float elements)
#define O_L1SEQ 0
#define O_L2SEQ 32768000
#define O_V1    36864000
#define O_V2    36995072
#define O_L1TR  37011456
#define O_L2TR  37142528

// ws layout (byte offsets). 4-slot rotating staging buffers (~3 MB total).
#define WS_XB    0          // bf16 [4][64][1024]  x_t as bf16 (A-op for gemm1)
#define WS_INTRT 524288     // bf16 [4][1024][64]  in_tr transposed (B-op for w_in update)
#define WS_L1B   1048576    // bf16 [4][64][2048]  l1 spikes (A-op for gemm2)
#define WS_L1TT  2097152    // bf16 [4][2048][64]  l1_tr transposed (B-op for w_hid update)
#define WS_FLAG  3145728    // int f_prep[256] f_l1done[256] f_l1step[256] f_l2done[256]

#define NB1 64     // layer-1 blocks: 32 h each, w_in slice resident
#define NB2 16     // layer-2 blocks: 16 o each, w_hid slice resident
#define NBLK 80
#define NTHR 512   // 8 waves

typedef __attribute__((ext_vector_type(8))) short short8v;
typedef __attribute__((ext_vector_type(4))) float float4v;

__device__ inline short f2bf(float f) {
  union { float f; uint32_t u; } c; c.f = f;
  uint32_t u = c.u + 0x7fffu + ((c.u >> 16) & 1u);  // RNE
  return (short)(u >> 16);
}

// XOR swizzles: 8-element (16 B) chunks XOR'd with (row&7) -> bank-conflict-free
__device__ inline int swz1024(int row, int k) {
  return row * 1024 + ((((k) >> 3) ^ (row & 7)) << 3) + ((k) & 7);
}
__device__ inline int swz2048(int row, int k) {
  return row * 2048 + ((((k) >> 3) ^ (row & 7)) << 3) + ((k) & 7);
}
__device__ inline int swz64(int row, int k) {
  return row * 64 + ((((k) >> 3) ^ (row & 7)) << 3) + ((k) & 7);
}

// ---- flag sync primitives (agent scope = device; crosses XCD L2s via LLC) ----
__device__ inline void spinflag(int* p, int target) {
  while (__hip_atomic_load(p, __ATOMIC_RELAXED, __HIP_MEMORY_SCOPE_AGENT) < target) {}
  (void)__hip_atomic_load(p, __ATOMIC_ACQUIRE, __HIP_MEMORY_SCOPE_AGENT);
}
__device__ inline void postflag(int* p) {
  __hip_atomic_fetch_add(p, 1, __ATOMIC_RELEASE, __HIP_MEMORY_SCOPE_AGENT);
}

struct SG1 {                 // layer-1 block LDS (86528 B)
  short winb[32 * 1024];     // bf16 shadow of w_in slice, swizzled
  float v1s[64 * 33];        // v1 state, padded
  float l1trs[64 * 33];      // l1_tr f32 state, padded
  short l1trT[32 * 64];      // l1_tr^T bf16 (A-op for w_in update), swizzled
};
struct SG2 {                 // layer-2 block LDS (80384 B)
  short whb[16 * 2048];      // bf16 shadow of w_hid slice, swizzled
  float v2s[64 * 17];
  float l2trs[64 * 17];
  short l2trT[16 * 64];      // swizzled
  float red[4 * 256];        // K-split reduce scratch
};

// Persistent kernel, point-to-point flag pipeline.
// L1 block phase t: wait slack-flags -> prep(t+1) -> gemm1(t) -> LIF1 -> publish
// -> w_in update(t). L2 block phase u: wait l1done[u] -> gemm2 -> LIF2 -> w_hid update.
__global__ __launch_bounds__(NTHR, 2) void kmain(const float* __restrict__ x,
                                                 const float* __restrict__ w_in,
                                                 const float* __restrict__ w_hid,
                                                 float* __restrict__ out,
                                                 char* __restrict__ ws) {
  __shared__ __align__(16) char smem[86528];
  cg::grid_group grid = cg::this_grid();
  const int bid = blockIdx.x, tid = threadIdx.x;
  const int lane = tid & 63, wv = tid >> 6;
  const int mr = lane & 15, q = lane >> 4;

  int* FB = (int*)(ws + WS_FLAG);
  int* FP = FB;          // f_prep[s]  : 64 posts when xb/intrT for step s written
  int* FD = FB + 256;    // f_l1done[s]: 64 posts when l1bg/l1tt slot s written
  int* FS = FB + 512;    // f_l1step[s]: 64 posts when L1 phase s fully done (reads incl.)
  int* FL2 = FB + 768;   // f_l2done[s]: 16 posts when L2 done reading step-s buffers

  // zero flags, publish via the single cooperative sync
  if (bid == 0) for (int c = tid; c < 1024; c += NTHR) FB[c] = 0;
  grid.sync();

  if (bid < NB1) {
    // ---------------- layer-1 block: owns w_in rows [h0, h0+32) ----------------
    SG1& S = *(SG1*)smem;
    const int h0 = bid * 32;
    const int bt = wv & 3, ht = wv >> 2;   // wave tile: b-tile, h-tile
    float wreg[64];                        // f32 w_in master
    float itr0, itr1;                      // thread-private in_tr state (2 elements)

    // prologue: load w_in slice -> regs + bf16 LDS shadow
#pragma unroll
    for (int j = 0; j < 16; j++) {
      const int it = (wv & 3) * 16 + j;
      const int i = it * 16 + mr;
#pragma unroll
      for (int r = 0; r < 4; r++) {
        const int hl = ht * 16 + q * 4 + r;
        float w = w_in[(h0 + hl) * INN + i];
        wreg[j * 4 + r] = w;
        S.winb[swz1024(hl, i)] = f2bf(w);
      }
    }
    for (int c = tid; c < 64 * 33; c += NTHR) { S.v1s[c] = 0.f; S.l1trs[c] = 0.f; }
    // prep step 0: in_tr(0) = (1-d)*x0; write slot 0
    {
      const int e2 = (bid * NTHR + tid) * 2, b = e2 >> 10, i = e2 & 1023;
      float2 xv = *(const float2*)(x + (b * TTT + 0) * INN + i);
      itr0 = (1.f - DECAYF) * xv.x;
      itr1 = (1.f - DECAYF) * xv.y;
      short* intT = (short*)(ws + WS_INTRT);
      short* xbp = (short*)(ws + WS_XB);
      short2 xb2; xb2.x = f2bf(xv.x); xb2.y = f2bf(xv.y);
      *(short2*)(xbp + e2) = xb2;
      intT[i * 64 + b] = f2bf(itr0);
      intT[(i + 1) * 64 + b] = f2bf(itr1);
    }
    __syncthreads();
    if (tid == 0) postflag(&FP[0]);

    for (int t = 0; t < TTT; t++) {
      const int sl = t & 3;
      // waits: xb/intrT(t) ready; slot (t+1)&3 free (L1 step t-3 done);
      // l1 slot t&3 free (L2 step t-4 done)
      if (tid == 0) {
        spinflag(&FP[t], 64);
        if (t >= 3) spinflag(&FS[t - 3], 64);
        if (t >= 4) spinflag(&FL2[t - 4], 16);
        __threadfence();
      }
      __syncthreads();

      // ---- prep(t+1), early: maximizes slack on the all-L1 exchange ----
      if (t + 1 < TTT) {
        const int sn = (t + 1) & 3;
        const int e2 = (bid * NTHR + tid) * 2, b = e2 >> 10, i = e2 & 1023;
        float2 xv = *(const float2*)(x + (b * TTT + (t + 1)) * INN + i);
        itr0 = DECAYF * itr0 + (1.f - DECAYF) * xv.x;
        itr1 = DECAYF * itr1 + (1.f - DECAYF) * xv.y;
        short* intT = (short*)(ws + WS_INTRT) + sn * (INN * BB);
        short* xbp = (short*)(ws + WS_XB) + sn * (BB * INN);
        short2 xb2; xb2.x = f2bf(xv.x); xb2.y = f2bf(xv.y);
        *(short2*)(xbp + e2) = xb2;
        intT[i * 64 + b] = f2bf(itr0);
        intT[(i + 1) * 64 + b] = f2bf(itr1);
        __syncthreads();
        if (tid == 0) postflag(&FP[t + 1]);
      }

      // ---- gemm1(t): cur1[64b x 32h] = x_t @ w_in^T, K=1024 ----
      const short* xb = (const short*)(ws + WS_XB) + sl * (BB * INN);
      float4v acc = {0.f, 0.f, 0.f, 0.f};
      {
        const short* xrow = xb + (bt * 16 + mr) * INN;
        const int brow = ht * 16 + mr;
#pragma unroll 8
        for (int ks = 0; ks < 32; ks++) {
          const int koff = ks * 32 + q * 8;
          short8v af = *(const short8v*)(xrow + koff);
          short8v bf = *(const short8v*)&S.winb[swz1024(brow, koff)];
          acc = __builtin_amdgcn_mfma_f32_16x16x32_bf16(af, bf, acc, 0, 0, 0);
        }
      }
      // ---- LIF1 + trace + publish l1 / l1_tr^T (slot sl) ----
      short* l1bg = (short*)(ws + WS_L1B) + sl * (BB * HIDD);
      short* l1ttg = (short*)(ws + WS_L1TT) + sl * (HIDD * BB);
      {
        const int hl = ht * 16 + mr, h = h0 + hl;
#pragma unroll
        for (int r = 0; r < 4; r++) {
          const int b = bt * 16 + q * 4 + r;
          float v = ALPHAF * S.v1s[b * 33 + hl] + SCLF * acc[r];
          float z = v > 1.0f ? 1.0f : 0.0f;
          v -= z;
          S.v1s[b * 33 + hl] = v;
          out[O_L1SEQ + (b * TTT + t) * HIDD + h] = z;
          l1bg[b * HIDD + h] = f2bf(z);
          float tr = DECAYF * S.l1trs[b * 33 + hl] + (1.f - DECAYF) * z;
          S.l1trs[b * 33 + hl] = tr;
          short tb = f2bf(tr);
          S.l1trT[swz64(hl, b)] = tb;
          l1ttg[h * 64 + b] = tb;
        }
      }
      __syncthreads();   // l1trT + l1bg/l1tt complete; winb reads done before update
      if (tid == 0) postflag(&FD[t]);

      // ---- w_in update: D[32h x 1024i] = l1_tr^T @ in_tr, K=64 ----
      {
        const short* intT = (const short*)(ws + WS_INTRT) + sl * (INN * BB);
        const int arow = ht * 16 + mr;
#pragma unroll
        for (int j = 0; j < 16; j++) {
          const int it = (wv & 3) * 16 + j;
          float4v a2 = {0.f, 0.f, 0.f, 0.f};
#pragma unroll
          for (int ks = 0; ks < 2; ks++) {
            const int koff = ks * 32 + q * 8;
            short8v af = *(const short8v*)&S.l1trT[swz64(arow, koff)];
            short8v bf = *(const short8v*)(intT + (it * 16 + mr) * 64 + koff);
            a2 = __builtin_amdgcn_mfma_f32_16x16x32_bf16(af, bf, a2, 0, 0, 0);
          }
          const int i = it * 16 + mr;
#pragma unroll
          for (int r = 0; r < 4; r++) {
            const int hl = ht * 16 + q * 4 + r;
            float w = wreg[j * 4 + r] * (1.f - LRF * WDF) + (LRF / 64.f) * a2[r];
            wreg[j * 4 + r] = w;
            S.winb[swz1024(hl, i)] = f2bf(w);
          }
        }
      }
      __syncthreads();   // all reads of step-t buffers done
      if (tid == 0) postflag(&FS[t]);
    }
    // epilogue: flush v1 / l1_tr
    for (int c = tid; c < 64 * 32; c += NTHR) {
      const int b = c >> 5, hl = c & 31;
      out[O_V1 + b * HIDD + h0 + hl] = S.v1s[b * 33 + hl];
      out[O_L1TR + b * HIDD + h0 + hl] = S.l1trs[b * 33 + hl];
    }
  } else {
    // ---------------- layer-2 block: owns w_hid rows [o0, o0+16) ----------------
    SG2& S = *(SG2*)smem;
    const int o0 = (bid - NB1) * 16;
    const int bt = wv & 3, kh = wv >> 2;   // b-tile, K-half
    float wreg[64];                        // f32 w_hid master

#pragma unroll
    for (int j = 0; j < 16; j++) {
      const int hcol = (wv * 16 + j) * 16 + mr;
#pragma unroll
      for (int r = 0; r < 4; r++) {
        const int ol = q * 4 + r;
        float w = w_hid[(o0 + ol) * HIDD + hcol];
        wreg[j * 4 + r] = w;
        S.whb[swz2048(ol, hcol)] = f2bf(w);
      }
    }
    for (int c = tid; c < 64 * 17; c += NTHR) { S.v2s[c] = 0.f; S.l2trs[c] = 0.f; }

    for (int u = 0; u < TTT; u++) {
      const int sl = u & 3;
      if (tid == 0) { spinflag(&FD[u], 64); __threadfence(); }
      __syncthreads();

      const short* l1bg = (const short*)(ws + WS_L1B) + sl * (BB * HIDD);
      // gemm2: cur2[64b x 16o] = l1 @ w_hid^T, K=2048 split 2 ways across waves
      float4v acc = {0.f, 0.f, 0.f, 0.f};
      {
        const short* arow = l1bg + (bt * 16 + mr) * HIDD + kh * 1024;
#pragma unroll 8
        for (int ks = 0; ks < 32; ks++) {
          const int kk = kh * 1024 + ks * 32 + q * 8;
          short8v af = *(const short8v*)(arow + ks * 32 + q * 8);
          short8v bf = *(const short8v*)&S.whb[swz2048(mr, kk)];
          acc = __builtin_amdgcn_mfma_f32_16x16x32_bf16(af, bf, acc, 0, 0, 0);
        }
      }
      if (kh == 1) { *(float4v*)&S.red[bt * 256 + lane * 4] = acc; }
      __syncthreads();
      if (kh == 0) {
        float4v o4 = *(const float4v*)&S.red[bt * 256 + lane * 4];
#pragma unroll
        for (int r = 0; r < 4; r++) {
          const int b = bt * 16 + q * 4 + r;
          float v = ALPHAF * S.v2s[b * 17 + mr] + SCLF * (acc[r] + o4[r]);
          float z = v > 1.0f ? 1.0f : 0.0f;
          v -= z;
          S.v2s[b * 17 + mr] = v;
          out[O_L2SEQ + (b * TTT + u) * OUTT + o0 + mr] = z;
          float tr = DECAYF * S.l2trs[b * 17 + mr] + (1.f - DECAYF) * z;
          S.l2trs[b * 17 + mr] = tr;
          S.l2trT[swz64(mr, b)] = f2bf(tr);
        }
      }
      __syncthreads();   // l2trT ready; whb reads done before update writes

      // w_hid update: D[16o x 2048h] = l2_tr^T @ l1_tr, K=64
      {
        const short* l1ttg = (const short*)(ws + WS_L1TT) + sl * (HIDD * BB);
#pragma unroll
        for (int j = 0; j < 16; j++) {
          const int htile = wv * 16 + j;
          float4v a2 = {0.f, 0.f, 0.f, 0.f};
#pragma unroll
          for (int ks = 0; ks < 2; ks++) {
            const int koff = ks * 32 + q * 8;
            short8v af = *(const short8v*)&S.l2trT[swz64(mr, koff)];
            short8v bf = *(const short8v*)(l1ttg + (htile * 16 + mr) * 64 + koff);
            a2 = __builtin_amdgcn_mfma_f32_16x16x32_bf16(af, bf, a2, 0, 0, 0);
          }
          const int hcol = htile * 16 + mr;
#pragma unroll
          for (int r = 0; r < 4; r++) {
            const int ol = q * 4 + r;
            float w = wreg[j * 4 + r] * (1.f - LRF * WDF) + (LRF / 64.f) * a2[r];
            wreg[j * 4 + r] = w;
            S.whb[swz2048(ol, hcol)] = f2bf(w);
          }
        }
      }
      __syncthreads();   // all reads of step-u buffers done
      if (tid == 0) postflag(&FL2[u]);
    }
    for (int c = tid; c < 64 * 16; c += NTHR) {
      const int b = c >> 4, ol = c & 15;
      out[O_V2 + b * OUTT + o0 + ol] = S.v2s[b * 17 + ol];
      out[O_L2TR + b * OUTT + o0 + ol] = S.l2trs[b * 17 + ol];
    }
  }
}

extern "C" void kernel_launch(void* const* d_in, const int* in_sizes, int n_in,
                              void* d_out, int out_size, void* d_ws, size_t ws_size,
                              hipStream_t stream) {
  const float* x = (const float*)d_in[0];
  const float* w_in = (const float*)d_in[1];
  const float* w_hid = (const float*)d_in[2];
  float* out = (float*)d_out;
  char* ws = (char*)d_ws;

  void* args[] = {(void*)&x, (void*)&w_in, (void*)&w_hid, (void*)&out, (void*)&ws};
  hipLaunchCooperativeKernel(reinterpret_cast<void*>(kmain), dim3(NBLK), dim3(NTHR),
                             args, 0, stream);
}